// Round 12
// baseline (112.562 us; speedup 1.0000x reference)
//
#include <hip/hip_runtime.h>
#include <math.h>

// Round-23: r22 post-mortem: dur 43.4 (best), conflicts 1.19M->500K. The
// residue is the phase-3 b32 gather (bank=(2t+parity)%32 -> 4-way when a
// wave's rows share parity), on the walk's critical path. Idle stuck at
// ~12.6us; its removable parts: (a) phase1->2 LDS round trip, (b) gather
// conflicts. Both fixed bit-exactly:
//  1. Intersection SoA pairs STAY IN REGISTERS through phase 2 (keys from
//     regs, phase 2 = zero LDS reads). LDS write (phase-3 gather only)
//     gets ~1000cy slack. +32 VGPR transient; LDS still the occupancy cap
//     (3 blocks/CU) so no occupancy loss up to ~100 VGPR.
//  2. Phase-3 gather: b64 pair read ldsXp[row>>1][tid] (bank=2t%32, r20's
//     measured-zero pattern) + parity cndmask. Conflicts -> ~0.
//  3. Keys: intersections first (frees 32 regs), corners last; sorts
//     interleaved to hide TRANS latency.
// All arithmetic bitwise r22 (passed at absmax 2^-8).
// FROZEN (bit-critical): atan2f/cosf/sinf + __f*_rn corner chain, mask
// ratios, masked sx/sy sum order, centroid FDIV, key function, cross order.

#define FMUL __fmul_rn
#define FADD __fadd_rn
#define FSUB __fsub_rn
#define FDIV __fdiv_rn

typedef float v2f __attribute__((ext_vector_type(2)));
__device__ __forceinline__ v2f v2(float a, float b) { v2f r; r.x = a; r.y = b; return r; }
__device__ __forceinline__ v2f vs(float a) { return v2(a, a); }
__device__ __forceinline__ float rcpf_(float x) { return __builtin_amdgcn_rcpf(x); }

// compare-exchange on packed keys: min -> pk[A], max -> pk[B]
#define CE(A,B) do { unsigned _x = pk[A], _y = pk[B]; \
                     pk[A] = _x < _y ? _x : _y; pk[B] = _x < _y ? _y : _x; } while (0)

// Batcher odd-even mergesort of pk[o..o+7], 19 CE
#define SORT8(o) do { \
    CE(o+0,o+1); CE(o+2,o+3); CE(o+0,o+2); CE(o+1,o+3); CE(o+1,o+2); \
    CE(o+4,o+5); CE(o+6,o+7); CE(o+4,o+6); CE(o+5,o+7); CE(o+5,o+6); \
    CE(o+0,o+4); CE(o+1,o+5); CE(o+2,o+6); CE(o+3,o+7); \
    CE(o+2,o+4); CE(o+3,o+5); \
    CE(o+1,o+2); CE(o+3,o+4); CE(o+5,o+6); } while (0)

// pk[0..7] sorted asc, pk[o..o+7] sorted asc ->
// pk[0..7] = lowest 8 of the 16, sorted (half-cleaner + bitonic-8).
#define MERGE_LOW8(o) do { \
    CE(0,o+7); CE(1,o+6); CE(2,o+5); CE(3,o+4); \
    CE(4,o+3); CE(5,o+2); CE(6,o+1); CE(7,o+0); \
    CE(0,4); CE(1,5); CE(2,6); CE(3,7); \
    CE(0,2); CE(1,3); CE(4,6); CE(5,7); \
    CE(0,1); CE(2,3); CE(4,5); CE(6,7); } while (0)

// u32 packed key (27-bit diamond-angle | 5-bit slot), monotone in atan2.
#define MAKEKEY(J, WX, WY, M, DST) do {                                     \
    float _dsum = FADD(fabsf(WX), fabsf(WY));                               \
    float _rs = (_dsum > 0.0f) ? FMUL((WX), rcpf_(_dsum)) : 1.0f;           \
    float _keyf = copysignf(FSUB(1.0f, _rs), (WY));                         \
    unsigned _sbk = __float_as_uint(_keyf);                                 \
    unsigned _u = _sbk ^ (unsigned)(((int)_sbk >> 31) | (int)0x80000000);   \
    (DST) = (M) ? ((_u & 0xFFFFFFE0u) | (unsigned)(J))                      \
                : (0xFFFFFFE0u | (unsigned)(J));                            \
} while (0)

// lane J (0..3) of an SoA pair array P[2] (compile-time J after unroll)
#define LN(P, J) (((J) & 1) ? P[(J) >> 1].y : P[(J) >> 1].x)

__global__
__attribute__((amdgpu_flat_work_group_size(256, 256), amdgpu_waves_per_eu(1)))
void riou_kernel(const float* __restrict__ pred,
                 const float* __restrict__ tgt,
                 float* __restrict__ out, int n)
{
    // Pair-major SoA planes: pair p holds slots (2p, 2p+1).
    // pairs 0..3 = corners (c1:0,1 c2:2,3), pairs 4..11 = intersections.
    // Pair-row stride 2048B == 0 mod 128 -> bank = 2*tid mod 32 for b64
    // ops incl. per-lane-dynamic pair rows (r20 measured-zero pattern);
    // per-thread column -> no barriers. 48KB -> 3 blocks/CU.
    __shared__ v2f ldsXp[12][256];
    __shared__ v2f ldsYp[12][256];
    const int tid = threadIdx.x;
    int i = blockIdx.x * blockDim.x + tid;
    if (i >= n) return;

    const float2* p2 = (const float2*)(pred + 6 * (size_t)i);
    const float2* q2 = (const float2*)(tgt  + 6 * (size_t)i);
    float2 pa = p2[0], pb = p2[1], pc2 = p2[2];
    float2 qa = q2[0], qb = q2[1], qc2 = q2[2];
    const float px = pa.x, py = pa.y, pw = pb.x, ph = pb.y;
    const float qx = qa.x, qy = qa.y, qw = qb.x, qh = qb.y;

    float area1 = FMUL(pw, ph), area2 = FMUL(qw, qh);

    // bit-critical transcendental sequence — DO NOT substitute identities
    float rad1 = atan2f(pc2.x, pc2.y);
    float cA = cosf(rad1), sA = sinf(rad1);
    float rad2 = atan2f(qc2.x, qc2.y);
    float cB = cosf(rad2), sB = sinf(rad2);

    // SoA corner pairs: [0] = corners 0,1; [1] = corners 2,3.
    v2f c1xp[2], c1yp[2], c2xp[2], c2yp[2];
    {
        const v2f dx01 = v2(0.5f, -0.5f), dx23 = v2(-0.5f, 0.5f);
        const v2f dy01 = v2(0.5f, 0.5f),  dy23 = v2(-0.5f, -0.5f);
        v2f cxx01 = dx01 * vs(pw), cxx23 = dx23 * vs(pw);
        v2f cyy01 = dy01 * vs(ph), cyy23 = dy23 * vs(ph);
        c1xp[0] = (cxx01 * vs(cA) - cyy01 * vs(sA)) + vs(px);
        c1xp[1] = (cxx23 * vs(cA) - cyy23 * vs(sA)) + vs(px);
        c1yp[0] = (cxx01 * vs(sA) + cyy01 * vs(cA)) + vs(py);
        c1yp[1] = (cxx23 * vs(sA) + cyy23 * vs(cA)) + vs(py);
        v2f qxx01 = dx01 * vs(qw), qxx23 = dx23 * vs(qw);
        v2f qyy01 = dy01 * vs(qh), qyy23 = dy23 * vs(qh);
        c2xp[0] = (qxx01 * vs(cB) - qyy01 * vs(sB)) + vs(qx);
        c2xp[1] = (qxx23 * vs(cB) - qyy23 * vs(sB)) + vs(qx);
        c2yp[0] = (qxx01 * vs(sB) + qyy01 * vs(cB)) + vs(qy);
        c2yp[1] = (qxx23 * vs(sB) + qyy23 * vs(cB)) + vs(qy);
    }
    // corner payload -> LDS (b64 straight from SoA regs; read in phase 3)
    ldsXp[0][tid] = c1xp[0]; ldsXp[1][tid] = c1xp[1];
    ldsXp[2][tid] = c2xp[0]; ldsXp[3][tid] = c2xp[1];
    ldsYp[0][tid] = c1yp[0]; ldsYp[1][tid] = c1yp[1];
    ldsYp[2][tid] = c2yp[0]; ldsYp[3][tid] = c2yp[1];

    // enclosing-box diagonal + center distance (original sequential order)
    float minx = c1xp[0].x, maxx = c1xp[0].x;
    float miny = c1yp[0].x, maxy = c1yp[0].x;
    minx = fminf(minx, c1xp[0].y); maxx = fmaxf(maxx, c1xp[0].y);
    miny = fminf(miny, c1yp[0].y); maxy = fmaxf(maxy, c1yp[0].y);
    minx = fminf(minx, c1xp[1].x); maxx = fmaxf(maxx, c1xp[1].x);
    miny = fminf(miny, c1yp[1].x); maxy = fmaxf(maxy, c1yp[1].x);
    minx = fminf(minx, c1xp[1].y); maxx = fmaxf(maxx, c1xp[1].y);
    miny = fminf(miny, c1yp[1].y); maxy = fmaxf(maxy, c1yp[1].y);
#pragma unroll
    for (int j = 0; j < 4; j++) {
        minx = fminf(minx, LN(c2xp, j)); maxx = fmaxf(maxx, LN(c2xp, j));
        miny = fminf(miny, LN(c2yp, j)); maxy = fmaxf(maxy, LN(c2yp, j));
    }
    float wcb = FSUB(maxx, minx), hcb = FSUB(maxy, miny);
    float c2d = FADD(FMUL(wcb, wcb), FMUL(hcb, hcb));
    float dxc = FSUB(px, qx), dyc = FSUB(py, qy);
    float d2 = FADD(FMUL(dxc, dxc), FMUL(dyc, dyc));

    // ---- phase 1: 24 candidate slots, mask bits + masked sums ----
    unsigned mbits = 0;
    v2f s2 = v2(0.0f, 0.0f);
    const v2f zero2 = v2(0.0f, 0.0f);
    const float eps = 1e-6f;
    const float hieps = 1.0f + 1e-6f;

    // slots 0-3: c1 corners inside c2 — pab/pad pairs cover 2 corners/op
    {
        float ax = c2xp[0].x, ay = c2yp[0].x;
        float abx = FSUB(c2xp[0].y, ax), aby = FSUB(c2yp[0].y, ay);
        float adx = FSUB(c2xp[1].y, ax), ady = FSUB(c2yp[1].y, ay);
        float rab = rcpf_(FADD(FMUL(abx, abx), FMUL(aby, aby)));
        float rad = rcpf_(FADD(FMUL(adx, adx), FMUL(ady, ady)));
        v2f amx01 = c1xp[0] - vs(ax), amx23 = c1xp[1] - vs(ax);
        v2f amy01 = c1yp[0] - vs(ay), amy23 = c1yp[1] - vs(ay);
        v2f pab01 = (vs(abx) * amx01 + vs(aby) * amy01) * vs(rab);
        v2f pab23 = (vs(abx) * amx23 + vs(aby) * amy23) * vs(rab);
        v2f pad01 = (vs(adx) * amx01 + vs(ady) * amy01) * vs(rad);
        v2f pad23 = (vs(adx) * amx23 + vs(ady) * amy23) * vs(rad);
#pragma unroll
        for (int j = 0; j < 4; j++) {
            float pab = (j < 2) ? ((j & 1) ? pab01.y : pab01.x)
                                : ((j & 1) ? pab23.y : pab23.x);
            float pad = (j < 2) ? ((j & 1) ? pad01.y : pad01.x)
                                : ((j & 1) ? pad23.y : pad23.x);
            int m = (pab > -eps) & (pab < hieps) & (pad > -eps) & (pad < hieps);
            mbits |= (unsigned)m << j;
            s2 = s2 + (m ? v2(LN(c1xp, j), LN(c1yp, j)) : zero2);
        }
    }
    // slots 4-7: c2 corners inside c1
    {
        float ax = c1xp[0].x, ay = c1yp[0].x;
        float abx = FSUB(c1xp[0].y, ax), aby = FSUB(c1yp[0].y, ay);
        float adx = FSUB(c1xp[1].y, ax), ady = FSUB(c1yp[1].y, ay);
        float rab = rcpf_(FADD(FMUL(abx, abx), FMUL(aby, aby)));
        float rad = rcpf_(FADD(FMUL(adx, adx), FMUL(ady, ady)));
        v2f amx01 = c2xp[0] - vs(ax), amx23 = c2xp[1] - vs(ax);
        v2f amy01 = c2yp[0] - vs(ay), amy23 = c2yp[1] - vs(ay);
        v2f pab01 = (vs(abx) * amx01 + vs(aby) * amy01) * vs(rab);
        v2f pab23 = (vs(abx) * amx23 + vs(aby) * amy23) * vs(rab);
        v2f pad01 = (vs(adx) * amx01 + vs(ady) * amy01) * vs(rad);
        v2f pad23 = (vs(adx) * amx23 + vs(ady) * amy23) * vs(rad);
#pragma unroll
        for (int j = 0; j < 4; j++) {
            float pab = (j < 2) ? ((j & 1) ? pab01.y : pab01.x)
                                : ((j & 1) ? pab23.y : pab23.x);
            float pad = (j < 2) ? ((j & 1) ? pad01.y : pad01.x)
                                : ((j & 1) ? pad23.y : pad23.x);
            int m = (pab > -eps) & (pab < hieps) & (pad > -eps) & (pad < hieps);
            mbits |= (unsigned)m << (4 + j);
            s2 = s2 + (m ? v2(LN(c2xp, j), LN(c2yp, j)) : zero2);
        }
    }
    // slots 8-23: edge intersections, two e2's per packed op.
    // Results kept in REGISTERS (rix/riy) for phase 2; stored to LDS only
    // for the phase-3 dynamic gather.
    v2f fexx01, fexx23, feyy01, feyy23;
    fexx01.x = FSUB(c2xp[0].y, c2xp[0].x);
    fexx01.y = FSUB(c2xp[1].x, c2xp[0].y);
    fexx23.x = FSUB(c2xp[1].y, c2xp[1].x);
    fexx23.y = FSUB(c2xp[0].x, c2xp[1].y);
    feyy01.x = FSUB(c2yp[0].y, c2yp[0].x);
    feyy01.y = FSUB(c2yp[1].x, c2yp[0].y);
    feyy23.x = FSUB(c2yp[1].y, c2yp[1].x);
    feyy23.y = FSUB(c2yp[0].x, c2yp[1].y);
    v2f rix[8], riy[8];                    // pair p: slots 8+2p, 9+2p
#pragma unroll
    for (int e1 = 0; e1 < 4; e1++) {
        float x1 = LN(c1xp, e1), y1 = LN(c1yp, e1);
        float xn = LN(c1xp, (e1 + 1) & 3), yn = LN(c1yp, (e1 + 1) & 3);
        float ex = FSUB(xn, x1), ey = FSUB(yn, y1);
        v2f d31x01 = c2xp[0] - vs(x1), d31x23 = c2xp[1] - vs(x1);
        v2f d31y01 = c2yp[0] - vs(y1), d31y23 = c2yp[1] - vs(y1);
        v2f numt01 = vs(ex) * d31y01 - vs(ey) * d31x01;
        v2f numt23 = vs(ex) * d31y23 - vs(ey) * d31x23;
        v2f dent01 = vs(ey) * fexx01 - vs(ex) * feyy01;
        v2f dent23 = vs(ey) * fexx23 - vs(ex) * feyy23;
        v2f rd01, rd23;
        rd01.x = rcpf_(dent01.x); rd01.y = rcpf_(dent01.y);
        rd23.x = rcpf_(dent23.x); rd23.y = rcpf_(dent23.y);
        v2f tq01 = numt01 * rd01, tq23 = numt23 * rd23;
        v2f numu01 = feyy01 * d31x01 - fexx01 * d31y01;
        v2f numu23 = feyy23 * d31x23 - fexx23 * d31y23;
        v2f uq01 = numu01 * rd01, uq23 = numu23 * rd23;   // == -u exactly
        v2f ixx01 = vs(x1) + tq01 * vs(ex), ixx23 = vs(x1) + tq23 * vs(ex);
        v2f iyy01 = vs(y1) + tq01 * vs(ey), iyy23 = vs(y1) + tq23 * vs(ey);
        rix[2 * e1] = ixx01; rix[2 * e1 + 1] = ixx23;
        riy[2 * e1] = iyy01; riy[2 * e1 + 1] = iyy23;
        int pbase = 4 + 2 * e1;
        ldsXp[pbase][tid]     = ixx01;
        ldsXp[pbase + 1][tid] = ixx23;
        ldsYp[pbase][tid]     = iyy01;
        ldsYp[pbase + 1][tid] = iyy23;
        int cb = 8 + 4 * e1;
#pragma unroll
        for (int e2 = 0; e2 < 4; e2++) {   // masks+sums in slot order
            float tq = (e2 < 2) ? ((e2 & 1) ? tq01.y : tq01.x)
                                : ((e2 & 1) ? tq23.y : tq23.x);
            float uq = (e2 < 2) ? ((e2 & 1) ? uq01.y : uq01.x)
                                : ((e2 & 1) ? uq23.y : uq23.x);
            float ixv = (e2 < 2) ? ((e2 & 1) ? ixx01.y : ixx01.x)
                                 : ((e2 & 1) ? ixx23.y : ixx23.x);
            float iyv = (e2 < 2) ? ((e2 & 1) ? iyy01.y : iyy01.x)
                                 : ((e2 & 1) ? iyy23.y : iyy23.x);
            int m = (tq > 0.0f) & (tq < 1.0f) & (uq < 0.0f) & (uq > -1.0f);
            mbits |= (unsigned)m << (cb + e2);
            s2 = s2 + (m ? v2(ixv, iyv) : zero2);
        }
    }

    int k = __popc(mbits);

    // centroid (IEEE div: feeds every recentered coordinate — bit-frozen)
    float kk = (float)(k > 0 ? k : 1);
    float mx = FDIV(s2.x, kk), my = FDIV(s2.y, kk);

    // ---- phase 2: keys — ALL from registers (zero LDS reads).
    // Intersections first (rix/riy die), corners last; sorts interleaved.
    unsigned pk[24];
#pragma unroll
    for (int p = 0; p < 4; p++) {          // slots 8..15
        v2f wx = rix[p] - vs(mx), wy = riy[p] - vs(my);
        int j = 8 + 2 * p;
        MAKEKEY(j,     wx.x, wy.x, (int)((mbits >> j) & 1u), pk[j]);
        MAKEKEY(j + 1, wx.y, wy.y, (int)((mbits >> (j + 1)) & 1u), pk[j + 1]);
    }
    SORT8(8);
#pragma unroll
    for (int p = 4; p < 8; p++) {          // slots 16..23
        v2f wx = rix[p] - vs(mx), wy = riy[p] - vs(my);
        int j = 8 + 2 * p;
        MAKEKEY(j,     wx.x, wy.x, (int)((mbits >> j) & 1u), pk[j]);
        MAKEKEY(j + 1, wx.y, wy.y, (int)((mbits >> (j + 1)) & 1u), pk[j + 1]);
    }
    SORT8(16);
    {   // corner keys (slots 0..7)
        v2f wx, wy;
        wx = c1xp[0] - vs(mx); wy = c1yp[0] - vs(my);
        MAKEKEY(0, wx.x, wy.x, (int)((mbits >> 0) & 1u), pk[0]);
        MAKEKEY(1, wx.y, wy.y, (int)((mbits >> 1) & 1u), pk[1]);
        wx = c1xp[1] - vs(mx); wy = c1yp[1] - vs(my);
        MAKEKEY(2, wx.x, wy.x, (int)((mbits >> 2) & 1u), pk[2]);
        MAKEKEY(3, wx.y, wy.y, (int)((mbits >> 3) & 1u), pk[3]);
        wx = c2xp[0] - vs(mx); wy = c2yp[0] - vs(my);
        MAKEKEY(4, wx.x, wy.x, (int)((mbits >> 4) & 1u), pk[4]);
        MAKEKEY(5, wx.y, wy.y, (int)((mbits >> 5) & 1u), pk[5]);
        wx = c2xp[1] - vs(mx); wy = c2yp[1] - vs(my);
        MAKEKEY(6, wx.x, wy.x, (int)((mbits >> 6) & 1u), pk[6]);
        MAKEKEY(7, wx.y, wy.y, (int)((mbits >> 7) & 1u), pk[7]);
    }
    SORT8(0);
    MERGE_LOW8(8);
    MERGE_LOW8(16);

    // ---- phase 3: 8 dynamic b64 pair gathers (bank=2t%32, conflict-free)
    // + parity cndmask select. Same pattern for both planes.
    v2f vpx[8], vpy[8];
#pragma unroll
    for (int s = 0; s < 8; s++) {
        unsigned pr = (pk[s] & 31u) >> 1;  // pair row in [0,12)
        vpx[s] = ldsXp[pr][tid];
        vpy[s] = ldsYp[pr][tid];
    }

    float firstx = 0.0f, firsty = 0.0f, prevx = 0.0f, prevy = 0.0f;
    float crs = 0.0f;
#pragma unroll
    for (int s = 0; s < 8; s++) {
        bool hi = (pk[s] & 1u) != 0u;      // slot parity
        float gx = FSUB(hi ? vpx[s].y : vpx[s].x, mx);
        float gy = FSUB(hi ? vpy[s].y : vpy[s].x, my);
        bool act = s < k;                  // inactive pass: payload -> prev
        float bx = act ? gx : prevx;
        float by = act ? gy : prevy;
        if (s == 0) { firstx = bx; firsty = by; }
        else {
            // inactive: cross(prev,prev) = exact IEEE 0 (identical products)
            crs = FADD(crs, FSUB(FMUL(prevx, by), FMUL(prevy, bx)));
        }
        prevx = bx; prevy = by;
    }
    // rare tail: noise masks can push k past the geometric bound of 8.
    // Leftovers in pk[8..23] all exceed pk[7] -> successive minima continue
    // the ascending order; keys unique -> sentinel removal removes one.
    if (k > 8) {
        for (int s = 8; s < k; s++) {
            unsigned mn = pk[8];
#pragma unroll
            for (int j = 9; j < 24; j++) mn = (pk[j] < mn) ? pk[j] : mn;
            unsigned row = mn & 31u;
            v2f vx2 = ldsXp[row >> 1][tid];
            v2f vy2 = ldsYp[row >> 1][tid];
            bool hi = (row & 1u) != 0u;
            float bx = FSUB(hi ? vx2.y : vx2.x, mx);
            float by = FSUB(hi ? vy2.y : vy2.x, my);
            crs = FADD(crs, FSUB(FMUL(prevx, by), FMUL(prevy, bx)));
            prevx = bx; prevy = by;
#pragma unroll
            for (int j = 8; j < 24; j++) if (pk[j] == mn) pk[j] = 0xFFFFFFFFu;
        }
    }
    // close the ring
    crs = FADD(crs, FSUB(FMUL(prevx, firsty), FMUL(prevy, firstx)));
    float inter = FMUL(0.5f, fabsf(crs));

    float uni = FSUB(FADD(area1, area2), inter);
    float iou = FMUL(inter, rcpf_(uni));

    out[i] = FADD(FSUB(1.0f, iou), FMUL(d2, rcpf_(c2d)));
}

extern "C" void kernel_launch(void* const* d_in, const int* in_sizes, int n_in,
                              void* d_out, int out_size, void* d_ws, size_t ws_size,
                              hipStream_t stream) {
    const float* pred = (const float*)d_in[0];
    const float* tgt  = (const float*)d_in[1];
    float* out = (float*)d_out;
    int n = in_sizes[0] / 6;
    int block = 256;
    int grid = (n + block - 1) / block;
    riou_kernel<<<grid, block, 0, stream>>>(pred, tgt, out, n);
}

// Round 13
// 110.888 us; speedup vs baseline: 1.0151x; 1.0151x over previous
//
#include <hip/hip_runtime.h>
#include <math.h>

// Round-24: r23 post-mortem: bundled two changes; one good, one bad.
//  - GOOD (kept here): phase-3 gather as b64 pair-read ldsXp[row>>1][tid]
//    (bank=2t%32, r23 measured ZERO conflicts) + parity cndmask.
//  - BAD (reverted): intersections resident in regs through phase 2 ->
//    live set past the 68-reg allocation -> latency-generating overflow
//    (idle 12.6->26us, busy 55%) at UNCHANGED product 31.6. This kernel
//    tolerates LDS round-trips (DS pipe free) far better than register
//    pressure (r19 lesson re-confirmed).
// So: r24 = r22 verbatim (best 43.4us, product 30.8, phase-2 batched LDS
// reads + interleaved sorts) with ONLY the phase-3/tail gather swapped to
// the pair-read + parity-select form. +16 cndmask ~= +0.25 product-units;
// removes the 500K 4-way-conflict reads from the walk's critical path.
// All arithmetic bitwise r22 (passed at absmax 2^-8).
// FROZEN (bit-critical): atan2f/cosf/sinf + __f*_rn corner chain, mask
// ratios, masked sx/sy sum order, centroid FDIV, key function, cross order.

#define FMUL __fmul_rn
#define FADD __fadd_rn
#define FSUB __fsub_rn
#define FDIV __fdiv_rn

typedef float v2f __attribute__((ext_vector_type(2)));
__device__ __forceinline__ v2f v2(float a, float b) { v2f r; r.x = a; r.y = b; return r; }
__device__ __forceinline__ v2f vs(float a) { return v2(a, a); }
__device__ __forceinline__ float rcpf_(float x) { return __builtin_amdgcn_rcpf(x); }

// compare-exchange on packed keys: min -> pk[A], max -> pk[B]
#define CE(A,B) do { unsigned _x = pk[A], _y = pk[B]; \
                     pk[A] = _x < _y ? _x : _y; pk[B] = _x < _y ? _y : _x; } while (0)

// Batcher odd-even mergesort of pk[o..o+7], 19 CE
#define SORT8(o) do { \
    CE(o+0,o+1); CE(o+2,o+3); CE(o+0,o+2); CE(o+1,o+3); CE(o+1,o+2); \
    CE(o+4,o+5); CE(o+6,o+7); CE(o+4,o+6); CE(o+5,o+7); CE(o+5,o+6); \
    CE(o+0,o+4); CE(o+1,o+5); CE(o+2,o+6); CE(o+3,o+7); \
    CE(o+2,o+4); CE(o+3,o+5); \
    CE(o+1,o+2); CE(o+3,o+4); CE(o+5,o+6); } while (0)

// pk[0..7] sorted asc, pk[o..o+7] sorted asc ->
// pk[0..7] = lowest 8 of the 16, sorted (half-cleaner + bitonic-8).
#define MERGE_LOW8(o) do { \
    CE(0,o+7); CE(1,o+6); CE(2,o+5); CE(3,o+4); \
    CE(4,o+3); CE(5,o+2); CE(6,o+1); CE(7,o+0); \
    CE(0,4); CE(1,5); CE(2,6); CE(3,7); \
    CE(0,2); CE(1,3); CE(4,6); CE(5,7); \
    CE(0,1); CE(2,3); CE(4,5); CE(6,7); } while (0)

// u32 packed key (27-bit diamond-angle | 5-bit slot), monotone in atan2.
#define MAKEKEY(J, WX, WY, M, DST) do {                                     \
    float _dsum = FADD(fabsf(WX), fabsf(WY));                               \
    float _rs = (_dsum > 0.0f) ? FMUL((WX), rcpf_(_dsum)) : 1.0f;           \
    float _keyf = copysignf(FSUB(1.0f, _rs), (WY));                         \
    unsigned _sbk = __float_as_uint(_keyf);                                 \
    unsigned _u = _sbk ^ (unsigned)(((int)_sbk >> 31) | (int)0x80000000);   \
    (DST) = (M) ? ((_u & 0xFFFFFFE0u) | (unsigned)(J))                      \
                : (0xFFFFFFE0u | (unsigned)(J));                            \
} while (0)

// lane J (0..3) of an SoA pair array P[2] (compile-time J after unroll)
#define LN(P, J) (((J) & 1) ? P[(J) >> 1].y : P[(J) >> 1].x)

__global__
__attribute__((amdgpu_flat_work_group_size(256, 256), amdgpu_waves_per_eu(1)))
void riou_kernel(const float* __restrict__ pred,
                 const float* __restrict__ tgt,
                 float* __restrict__ out, int n)
{
    // Pair-major SoA planes: pair p holds slots (2p, 2p+1).
    // pairs 0..3 = corners (c1:0,1 c2:2,3), pairs 4..11 = intersections.
    // Pair-row stride 2048B == 0 mod 128 -> bank = 2*tid mod 32 for b64
    // ops incl. per-lane-dynamic pair rows (r20/r23 measured-zero
    // pattern); per-thread column -> no barriers. 48KB -> 3 blocks/CU.
    __shared__ v2f ldsXp[12][256];
    __shared__ v2f ldsYp[12][256];
    const int tid = threadIdx.x;
    int i = blockIdx.x * blockDim.x + tid;
    if (i >= n) return;

    const float2* p2 = (const float2*)(pred + 6 * (size_t)i);
    const float2* q2 = (const float2*)(tgt  + 6 * (size_t)i);
    float2 pa = p2[0], pb = p2[1], pc2 = p2[2];
    float2 qa = q2[0], qb = q2[1], qc2 = q2[2];
    const float px = pa.x, py = pa.y, pw = pb.x, ph = pb.y;
    const float qx = qa.x, qy = qa.y, qw = qb.x, qh = qb.y;

    float area1 = FMUL(pw, ph), area2 = FMUL(qw, qh);

    // bit-critical transcendental sequence — DO NOT substitute identities
    float rad1 = atan2f(pc2.x, pc2.y);
    float cA = cosf(rad1), sA = sinf(rad1);
    float rad2 = atan2f(qc2.x, qc2.y);
    float cB = cosf(rad2), sB = sinf(rad2);

    // SoA corner pairs: [0] = corners 0,1; [1] = corners 2,3.
    v2f c1xp[2], c1yp[2], c2xp[2], c2yp[2];
    {
        const v2f dx01 = v2(0.5f, -0.5f), dx23 = v2(-0.5f, 0.5f);
        const v2f dy01 = v2(0.5f, 0.5f),  dy23 = v2(-0.5f, -0.5f);
        v2f cxx01 = dx01 * vs(pw), cxx23 = dx23 * vs(pw);
        v2f cyy01 = dy01 * vs(ph), cyy23 = dy23 * vs(ph);
        c1xp[0] = (cxx01 * vs(cA) - cyy01 * vs(sA)) + vs(px);
        c1xp[1] = (cxx23 * vs(cA) - cyy23 * vs(sA)) + vs(px);
        c1yp[0] = (cxx01 * vs(sA) + cyy01 * vs(cA)) + vs(py);
        c1yp[1] = (cxx23 * vs(sA) + cyy23 * vs(cA)) + vs(py);
        v2f qxx01 = dx01 * vs(qw), qxx23 = dx23 * vs(qw);
        v2f qyy01 = dy01 * vs(qh), qyy23 = dy23 * vs(qh);
        c2xp[0] = (qxx01 * vs(cB) - qyy01 * vs(sB)) + vs(qx);
        c2xp[1] = (qxx23 * vs(cB) - qyy23 * vs(sB)) + vs(qx);
        c2yp[0] = (qxx01 * vs(sB) + qyy01 * vs(cB)) + vs(qy);
        c2yp[1] = (qxx23 * vs(sB) + qyy23 * vs(cB)) + vs(qy);
    }
    // corner payload -> LDS (single b64 per pair, straight from SoA regs)
    ldsXp[0][tid] = c1xp[0]; ldsXp[1][tid] = c1xp[1];
    ldsXp[2][tid] = c2xp[0]; ldsXp[3][tid] = c2xp[1];
    ldsYp[0][tid] = c1yp[0]; ldsYp[1][tid] = c1yp[1];
    ldsYp[2][tid] = c2yp[0]; ldsYp[3][tid] = c2yp[1];

    // enclosing-box diagonal + center distance (original sequential order)
    float minx = c1xp[0].x, maxx = c1xp[0].x;
    float miny = c1yp[0].x, maxy = c1yp[0].x;
    minx = fminf(minx, c1xp[0].y); maxx = fmaxf(maxx, c1xp[0].y);
    miny = fminf(miny, c1yp[0].y); maxy = fmaxf(maxy, c1yp[0].y);
    minx = fminf(minx, c1xp[1].x); maxx = fmaxf(maxx, c1xp[1].x);
    miny = fminf(miny, c1yp[1].x); maxy = fmaxf(maxy, c1yp[1].x);
    minx = fminf(minx, c1xp[1].y); maxx = fmaxf(maxx, c1xp[1].y);
    miny = fminf(miny, c1yp[1].y); maxy = fmaxf(maxy, c1yp[1].y);
#pragma unroll
    for (int j = 0; j < 4; j++) {
        minx = fminf(minx, LN(c2xp, j)); maxx = fmaxf(maxx, LN(c2xp, j));
        miny = fminf(miny, LN(c2yp, j)); maxy = fmaxf(maxy, LN(c2yp, j));
    }
    float wcb = FSUB(maxx, minx), hcb = FSUB(maxy, miny);
    float c2d = FADD(FMUL(wcb, wcb), FMUL(hcb, hcb));
    float dxc = FSUB(px, qx), dyc = FSUB(py, qy);
    float d2 = FADD(FMUL(dxc, dxc), FMUL(dyc, dyc));

    // ---- phase 1: 24 candidate slots, mask bits + masked sums ----
    unsigned mbits = 0;
    v2f s2 = v2(0.0f, 0.0f);
    const v2f zero2 = v2(0.0f, 0.0f);
    const float eps = 1e-6f;
    const float hieps = 1.0f + 1e-6f;

    // slots 0-3: c1 corners inside c2 — pab/pad pairs cover 2 corners/op
    {
        float ax = c2xp[0].x, ay = c2yp[0].x;
        float abx = FSUB(c2xp[0].y, ax), aby = FSUB(c2yp[0].y, ay);
        float adx = FSUB(c2xp[1].y, ax), ady = FSUB(c2yp[1].y, ay);
        float rab = rcpf_(FADD(FMUL(abx, abx), FMUL(aby, aby)));
        float rad = rcpf_(FADD(FMUL(adx, adx), FMUL(ady, ady)));
        v2f amx01 = c1xp[0] - vs(ax), amx23 = c1xp[1] - vs(ax);
        v2f amy01 = c1yp[0] - vs(ay), amy23 = c1yp[1] - vs(ay);
        v2f pab01 = (vs(abx) * amx01 + vs(aby) * amy01) * vs(rab);
        v2f pab23 = (vs(abx) * amx23 + vs(aby) * amy23) * vs(rab);
        v2f pad01 = (vs(adx) * amx01 + vs(ady) * amy01) * vs(rad);
        v2f pad23 = (vs(adx) * amx23 + vs(ady) * amy23) * vs(rad);
#pragma unroll
        for (int j = 0; j < 4; j++) {
            float pab = (j < 2) ? ((j & 1) ? pab01.y : pab01.x)
                                : ((j & 1) ? pab23.y : pab23.x);
            float pad = (j < 2) ? ((j & 1) ? pad01.y : pad01.x)
                                : ((j & 1) ? pad23.y : pad23.x);
            int m = (pab > -eps) & (pab < hieps) & (pad > -eps) & (pad < hieps);
            mbits |= (unsigned)m << j;
            s2 = s2 + (m ? v2(LN(c1xp, j), LN(c1yp, j)) : zero2);
        }
    }
    // slots 4-7: c2 corners inside c1
    {
        float ax = c1xp[0].x, ay = c1yp[0].x;
        float abx = FSUB(c1xp[0].y, ax), aby = FSUB(c1yp[0].y, ay);
        float adx = FSUB(c1xp[1].y, ax), ady = FSUB(c1yp[1].y, ay);
        float rab = rcpf_(FADD(FMUL(abx, abx), FMUL(aby, aby)));
        float rad = rcpf_(FADD(FMUL(adx, adx), FMUL(ady, ady)));
        v2f amx01 = c2xp[0] - vs(ax), amx23 = c2xp[1] - vs(ax);
        v2f amy01 = c2yp[0] - vs(ay), amy23 = c2yp[1] - vs(ay);
        v2f pab01 = (vs(abx) * amx01 + vs(aby) * amy01) * vs(rab);
        v2f pab23 = (vs(abx) * amx23 + vs(aby) * amy23) * vs(rab);
        v2f pad01 = (vs(adx) * amx01 + vs(ady) * amy01) * vs(rad);
        v2f pad23 = (vs(adx) * amx23 + vs(ady) * amy23) * vs(rad);
#pragma unroll
        for (int j = 0; j < 4; j++) {
            float pab = (j < 2) ? ((j & 1) ? pab01.y : pab01.x)
                                : ((j & 1) ? pab23.y : pab23.x);
            float pad = (j < 2) ? ((j & 1) ? pad01.y : pad01.x)
                                : ((j & 1) ? pad23.y : pad23.x);
            int m = (pab > -eps) & (pab < hieps) & (pad > -eps) & (pad < hieps);
            mbits |= (unsigned)m << (4 + j);
            s2 = s2 + (m ? v2(LN(c2xp, j), LN(c2yp, j)) : zero2);
        }
    }
    // slots 8-23: edge intersections, two e2's per packed op.
    v2f fexx01, fexx23, feyy01, feyy23;
    fexx01.x = FSUB(c2xp[0].y, c2xp[0].x);
    fexx01.y = FSUB(c2xp[1].x, c2xp[0].y);
    fexx23.x = FSUB(c2xp[1].y, c2xp[1].x);
    fexx23.y = FSUB(c2xp[0].x, c2xp[1].y);
    feyy01.x = FSUB(c2yp[0].y, c2yp[0].x);
    feyy01.y = FSUB(c2yp[1].x, c2yp[0].y);
    feyy23.x = FSUB(c2yp[1].y, c2yp[1].x);
    feyy23.y = FSUB(c2yp[0].x, c2yp[1].y);
#pragma unroll
    for (int e1 = 0; e1 < 4; e1++) {
        float x1 = LN(c1xp, e1), y1 = LN(c1yp, e1);
        float xn = LN(c1xp, (e1 + 1) & 3), yn = LN(c1yp, (e1 + 1) & 3);
        float ex = FSUB(xn, x1), ey = FSUB(yn, y1);
        v2f d31x01 = c2xp[0] - vs(x1), d31x23 = c2xp[1] - vs(x1);
        v2f d31y01 = c2yp[0] - vs(y1), d31y23 = c2yp[1] - vs(y1);
        v2f numt01 = vs(ex) * d31y01 - vs(ey) * d31x01;
        v2f numt23 = vs(ex) * d31y23 - vs(ey) * d31x23;
        v2f dent01 = vs(ey) * fexx01 - vs(ex) * feyy01;
        v2f dent23 = vs(ey) * fexx23 - vs(ex) * feyy23;
        v2f rd01, rd23;
        rd01.x = rcpf_(dent01.x); rd01.y = rcpf_(dent01.y);
        rd23.x = rcpf_(dent23.x); rd23.y = rcpf_(dent23.y);
        v2f tq01 = numt01 * rd01, tq23 = numt23 * rd23;
        v2f numu01 = feyy01 * d31x01 - fexx01 * d31y01;
        v2f numu23 = feyy23 * d31x23 - fexx23 * d31y23;
        v2f uq01 = numu01 * rd01, uq23 = numu23 * rd23;   // == -u exactly
        v2f ixx01 = vs(x1) + tq01 * vs(ex), ixx23 = vs(x1) + tq23 * vs(ex);
        v2f iyy01 = vs(y1) + tq01 * vs(ey), iyy23 = vs(y1) + tq23 * vs(ey);
        int pbase = 4 + 2 * e1;            // pair rows for slots 8+4e1 ..
        ldsXp[pbase][tid]     = ixx01;
        ldsXp[pbase + 1][tid] = ixx23;
        ldsYp[pbase][tid]     = iyy01;
        ldsYp[pbase + 1][tid] = iyy23;
        int cb = 8 + 4 * e1;
#pragma unroll
        for (int e2 = 0; e2 < 4; e2++) {   // masks+sums in slot order
            float tq = (e2 < 2) ? ((e2 & 1) ? tq01.y : tq01.x)
                                : ((e2 & 1) ? tq23.y : tq23.x);
            float uq = (e2 < 2) ? ((e2 & 1) ? uq01.y : uq01.x)
                                : ((e2 & 1) ? uq23.y : uq23.x);
            float ixv = (e2 < 2) ? ((e2 & 1) ? ixx01.y : ixx01.x)
                                 : ((e2 & 1) ? ixx23.y : ixx23.x);
            float iyv = (e2 < 2) ? ((e2 & 1) ? iyy01.y : iyy01.x)
                                 : ((e2 & 1) ? iyy23.y : iyy23.x);
            int m = (tq > 0.0f) & (tq < 1.0f) & (uq < 0.0f) & (uq > -1.0f);
            mbits |= (unsigned)m << (cb + e2);
            s2 = s2 + (m ? v2(ixv, iyv) : zero2);
        }
    }

    int k = __popc(mbits);

    // centroid (IEEE div: feeds every recentered coordinate — bit-frozen)
    float kk = (float)(k > 0 ? k : 1);
    float mx = FDIV(s2.x, kk), my = FDIV(s2.y, kk);

    // ---- phase 2: keys; b64 pair-reads batched, sort interleaved ----
    unsigned pk[24];
    v2f bx0 = ldsXp[4][tid], bx1 = ldsXp[5][tid];
    v2f bx2 = ldsXp[6][tid], bx3 = ldsXp[7][tid];
    v2f by0 = ldsYp[4][tid], by1 = ldsYp[5][tid];
    v2f by2 = ldsYp[6][tid], by3 = ldsYp[7][tid];
    {   // corner keys from regs while batch A is in flight
        v2f wx, wy;
        wx = c1xp[0] - vs(mx); wy = c1yp[0] - vs(my);
        MAKEKEY(0, wx.x, wy.x, (int)((mbits >> 0) & 1u), pk[0]);
        MAKEKEY(1, wx.y, wy.y, (int)((mbits >> 1) & 1u), pk[1]);
        wx = c1xp[1] - vs(mx); wy = c1yp[1] - vs(my);
        MAKEKEY(2, wx.x, wy.x, (int)((mbits >> 2) & 1u), pk[2]);
        MAKEKEY(3, wx.y, wy.y, (int)((mbits >> 3) & 1u), pk[3]);
        wx = c2xp[0] - vs(mx); wy = c2yp[0] - vs(my);
        MAKEKEY(4, wx.x, wy.x, (int)((mbits >> 4) & 1u), pk[4]);
        MAKEKEY(5, wx.y, wy.y, (int)((mbits >> 5) & 1u), pk[5]);
        wx = c2xp[1] - vs(mx); wy = c2yp[1] - vs(my);
        MAKEKEY(6, wx.x, wy.x, (int)((mbits >> 6) & 1u), pk[6]);
        MAKEKEY(7, wx.y, wy.y, (int)((mbits >> 7) & 1u), pk[7]);
    }
    SORT8(0);                        // pure VALU while batch A in flight
    {
        v2f wx, wy;
        wx = bx0 - vs(mx); wy = by0 - vs(my);
        MAKEKEY(8, wx.x, wy.x, (int)((mbits >> 8) & 1u), pk[8]);
        MAKEKEY(9, wx.y, wy.y, (int)((mbits >> 9) & 1u), pk[9]);
        wx = bx1 - vs(mx); wy = by1 - vs(my);
        MAKEKEY(10, wx.x, wy.x, (int)((mbits >> 10) & 1u), pk[10]);
        MAKEKEY(11, wx.y, wy.y, (int)((mbits >> 11) & 1u), pk[11]);
        wx = bx2 - vs(mx); wy = by2 - vs(my);
        MAKEKEY(12, wx.x, wy.x, (int)((mbits >> 12) & 1u), pk[12]);
        MAKEKEY(13, wx.y, wy.y, (int)((mbits >> 13) & 1u), pk[13]);
        wx = bx3 - vs(mx); wy = by3 - vs(my);
        MAKEKEY(14, wx.x, wy.x, (int)((mbits >> 14) & 1u), pk[14]);
        MAKEKEY(15, wx.y, wy.y, (int)((mbits >> 15) & 1u), pk[15]);
    }
    // batch B issue (pairs 8..11 = slots 16..23), sort while in flight
    bx0 = ldsXp[8][tid];  bx1 = ldsXp[9][tid];
    bx2 = ldsXp[10][tid]; bx3 = ldsXp[11][tid];
    by0 = ldsYp[8][tid];  by1 = ldsYp[9][tid];
    by2 = ldsYp[10][tid]; by3 = ldsYp[11][tid];
    SORT8(8);                        // pure VALU while batch B in flight
    {
        v2f wx, wy;
        wx = bx0 - vs(mx); wy = by0 - vs(my);
        MAKEKEY(16, wx.x, wy.x, (int)((mbits >> 16) & 1u), pk[16]);
        MAKEKEY(17, wx.y, wy.y, (int)((mbits >> 17) & 1u), pk[17]);
        wx = bx1 - vs(mx); wy = by1 - vs(my);
        MAKEKEY(18, wx.x, wy.x, (int)((mbits >> 18) & 1u), pk[18]);
        MAKEKEY(19, wx.y, wy.y, (int)((mbits >> 19) & 1u), pk[19]);
        wx = bx2 - vs(mx); wy = by2 - vs(my);
        MAKEKEY(20, wx.x, wy.x, (int)((mbits >> 20) & 1u), pk[20]);
        MAKEKEY(21, wx.y, wy.y, (int)((mbits >> 21) & 1u), pk[21]);
        wx = bx3 - vs(mx); wy = by3 - vs(my);
        MAKEKEY(22, wx.x, wy.x, (int)((mbits >> 22) & 1u), pk[22]);
        MAKEKEY(23, wx.y, wy.y, (int)((mbits >> 23) & 1u), pk[23]);
    }

    SORT8(16);
    MERGE_LOW8(8);
    MERGE_LOW8(16);

    // ---- phase 3: 8 dynamic b64 pair gathers (bank=2t%32, conflict-free
    // per r23 measurement) + parity cndmask. Same pattern for both planes.
    v2f vpx[8], vpy[8];
#pragma unroll
    for (int s = 0; s < 8; s++) {
        unsigned pr = (pk[s] & 31u) >> 1;  // pair row in [0,12)
        vpx[s] = ldsXp[pr][tid];
        vpy[s] = ldsYp[pr][tid];
    }

    float firstx = 0.0f, firsty = 0.0f, prevx = 0.0f, prevy = 0.0f;
    float crs = 0.0f;
#pragma unroll
    for (int s = 0; s < 8; s++) {
        bool hi = (pk[s] & 1u) != 0u;      // slot parity
        float gx = FSUB(hi ? vpx[s].y : vpx[s].x, mx);
        float gy = FSUB(hi ? vpy[s].y : vpy[s].x, my);
        bool act = s < k;                  // inactive pass: payload -> prev
        float bx = act ? gx : prevx;
        float by = act ? gy : prevy;
        if (s == 0) { firstx = bx; firsty = by; }
        else {
            // inactive: cross(prev,prev) = exact IEEE 0 (identical products)
            crs = FADD(crs, FSUB(FMUL(prevx, by), FMUL(prevy, bx)));
        }
        prevx = bx; prevy = by;
    }
    // rare tail: noise masks can push k past the geometric bound of 8.
    // Leftovers in pk[8..23] all exceed pk[7] -> successive minima continue
    // the ascending order; keys unique -> sentinel removal removes one.
    if (k > 8) {
        for (int s = 8; s < k; s++) {
            unsigned mn = pk[8];
#pragma unroll
            for (int j = 9; j < 24; j++) mn = (pk[j] < mn) ? pk[j] : mn;
            unsigned row = mn & 31u;
            v2f vx2 = ldsXp[row >> 1][tid];
            v2f vy2 = ldsYp[row >> 1][tid];
            bool hi = (row & 1u) != 0u;
            float bx = FSUB(hi ? vx2.y : vx2.x, mx);
            float by = FSUB(hi ? vy2.y : vy2.x, my);
            crs = FADD(crs, FSUB(FMUL(prevx, by), FMUL(prevy, bx)));
            prevx = bx; prevy = by;
#pragma unroll
            for (int j = 8; j < 24; j++) if (pk[j] == mn) pk[j] = 0xFFFFFFFFu;
        }
    }
    // close the ring
    crs = FADD(crs, FSUB(FMUL(prevx, firsty), FMUL(prevy, firstx)));
    float inter = FMUL(0.5f, fabsf(crs));

    float uni = FSUB(FADD(area1, area2), inter);
    float iou = FMUL(inter, rcpf_(uni));

    out[i] = FADD(FSUB(1.0f, iou), FMUL(d2, rcpf_(c2d)));
}

extern "C" void kernel_launch(void* const* d_in, const int* in_sizes, int n_in,
                              void* d_out, int out_size, void* d_ws, size_t ws_size,
                              hipStream_t stream) {
    const float* pred = (const float*)d_in[0];
    const float* tgt  = (const float*)d_in[1];
    float* out = (float*)d_out;
    int n = in_sizes[0] / 6;
    int block = 256;
    int grid = (n + block - 1) / block;
    riou_kernel<<<grid, block, 0, stream>>>(pred, tgt, out, n);
}